// Round 1
// baseline (161.029 us; speedup 1.0000x reference)
//
#include <hip/hip_runtime.h>
#include <hip/hip_bf16.h>

#define NN 100000       // nodes
#define DD 128          // emb dim (also PQ width: 64 P + 64 Q)
#define EHn 400000      // half-edge count
#define BIASc 1e-4f

using bf16x8 = __attribute__((ext_vector_type(8))) __bf16;
using f32x4  = __attribute__((ext_vector_type(4))) float;

// workspace layout
#define PQ_OFF    0
#define PQ_BYTES  ((size_t)NN * DD * 2)          // 25,600,000 (16B aligned)
#define BFRAG_OFF PQ_BYTES
#define BFRAG_BYTES (4 * 8 * 64 * 8 * 2)         // 32768
#define PART_OFF  (BFRAG_OFF + BFRAG_BYTES)
#define NBLK_EDGE 2048

// ---------------------------------------------------------------------------
// Kernel 1: repack W1 (fp32, [256][64] row-major) into bf16 MFMA B-fragments.
// W1cat[k][c] (k<128, c<128): c<64 -> W1[k][c] (top half), c>=64 -> W1[k+128][c-64].
// Fragment (t,f): k = t*32 + (lane>>4)*8 + j, col = f*16 + (lane&15), j=0..7.
// Flat layout: bfrag[((t*8+f)*64 + lane)*8 + j]
// ---------------------------------------------------------------------------
__global__ void w1_repack_kernel(const float* __restrict__ W1, __bf16* __restrict__ bfrag) {
    #pragma unroll
    for (int i = 0; i < 64; ++i) {
        int idx = threadIdx.x + i * 256;          // 0..16383
        int j = idx & 7;
        int l = (idx >> 3) & 63;
        int f = (idx >> 9) & 7;
        int t = idx >> 12;
        int k = t * 32 + ((l >> 4) << 3) + j;
        int c = f * 16 + (l & 15);
        float v = (c < 64) ? W1[k * 64 + c] : W1[(k + 128) * 64 + (c - 64)];
        bfrag[idx] = (__bf16)v;
    }
}

// ---------------------------------------------------------------------------
// Kernel 2: PQ = emb @ W1cat  (100000x128 @ 128x128, bf16 MFMA, fp32 acc)
// Block = 4 waves, 128 rows/block; wave handles 32 rows x 128 cols.
// A-frags straight from global fp32 (cvt inline); B-frags from ws (L1-resident).
// ---------------------------------------------------------------------------
__global__ __launch_bounds__(256)
void node_proj_kernel(const float* __restrict__ emb, const __bf16* __restrict__ bfragG,
                      __bf16* __restrict__ PQ) {
    const int lane = threadIdx.x & 63;
    const int wave = threadIdx.x >> 6;
    const int rowBase = blockIdx.x * 128 + wave * 32;
    const int r16 = lane & 15;
    const int kg  = lane >> 4;

    f32x4 acc[2][8];
    #pragma unroll
    for (int m = 0; m < 2; ++m)
        #pragma unroll
        for (int f = 0; f < 8; ++f)
            acc[m][f] = (f32x4){0.f, 0.f, 0.f, 0.f};

    const bf16x8* bfrag = (const bf16x8*)bfragG;

    #pragma unroll
    for (int t = 0; t < 4; ++t) {
        bf16x8 af[2];
        #pragma unroll
        for (int m = 0; m < 2; ++m) {
            int row = rowBase + m * 16 + r16;
            row = row < NN ? row : NN - 1;        // clamp tail (stores guarded)
            const float* ap = emb + (size_t)row * DD + t * 32 + kg * 8;
            float4 lo = *(const float4*)ap;
            float4 hi = *(const float4*)(ap + 4);
            bf16x8 v;
            v[0] = (__bf16)lo.x; v[1] = (__bf16)lo.y; v[2] = (__bf16)lo.z; v[3] = (__bf16)lo.w;
            v[4] = (__bf16)hi.x; v[5] = (__bf16)hi.y; v[6] = (__bf16)hi.z; v[7] = (__bf16)hi.w;
            af[m] = v;
        }
        #pragma unroll
        for (int f = 0; f < 8; ++f) {
            bf16x8 bf = bfrag[(t * 8 + f) * 64 + lane];
            #pragma unroll
            for (int m = 0; m < 2; ++m)
                acc[m][f] = __builtin_amdgcn_mfma_f32_16x16x32_bf16(af[m], bf, acc[m][f], 0, 0, 0);
        }
    }

    // C/D layout (m89-verified): col = lane&15, row = (lane>>4)*4 + r
    #pragma unroll
    for (int m = 0; m < 2; ++m) {
        #pragma unroll
        for (int f = 0; f < 8; ++f) {
            #pragma unroll
            for (int r = 0; r < 4; ++r) {
                int row = rowBase + m * 16 + kg * 4 + r;
                int col = f * 16 + r16;
                if (row < NN) PQ[(size_t)row * DD + col] = (__bf16)acc[m][f][r];
            }
        }
    }
}

// ---------------------------------------------------------------------------
// Kernel 3: per-edge gate. One wave per edge (grid-stride). Lane i owns
// hidden unit i: h = relu(P[src][i] + Q[dst][i] + b1[i]); butterfly-reduce
// h*W2[i] -> logit; concrete gate; write new_vals twice; per-block partial sum.
// ---------------------------------------------------------------------------
__global__ __launch_bounds__(256)
void edge_kernel(const __bf16* __restrict__ PQ, const int* __restrict__ src,
                 const int* __restrict__ dst, const float* __restrict__ vals,
                 const float* __restrict__ eps_u, const float* __restrict__ b1,
                 const float* __restrict__ W2, const float* __restrict__ b2,
                 float* __restrict__ out, float* __restrict__ partials) {
    const int lane = threadIdx.x & 63;
    const int waveInBlk = threadIdx.x >> 6;
    const int gw = (int)((blockIdx.x * blockDim.x + threadIdx.x) >> 6);
    const int nw = (int)((gridDim.x * blockDim.x) >> 6);

    const float b1l = b1[lane];
    const float w2l = W2[lane];
    const float b2s = b2[0];

    float accw = 0.f;
    for (int e = gw; e < EHn; e += nw) {
        int s = src[e];
        int d = dst[e];
        float p = (float)PQ[s * DD + lane];
        float q = (float)PQ[d * DD + 64 + lane];
        float h = fmaxf(p + q + b1l, 0.f);
        float c = h * w2l;
        #pragma unroll
        for (int off = 32; off > 0; off >>= 1)
            c += __shfl_xor(c, off, 64);
        if (lane == 0) {
            float logit = c + b2s;
            float u = eps_u[e];
            float eps = (2.f * BIASc - 1.f) * u + (1.f - BIASc);   // in [BIAS, 1-BIAS]
            float g = __logf(eps) - log1pf(-eps) + logit;          // TEMP = 1
            float w = 1.f / (1.f + __expf(-g));
            float nv = vals[e] * w;
            out[e] = nv;
            out[EHn + e] = nv;
            accw += w;
        }
    }

    __shared__ float sacc[4];
    if (lane == 0) sacc[waveInBlk] = accw;
    __syncthreads();
    if (threadIdx.x == 0)
        partials[blockIdx.x] = sacc[0] + sacc[1] + sacc[2] + sacc[3];
}

// ---------------------------------------------------------------------------
// Kernel 4: deterministic mean reduction over block partials.
// ---------------------------------------------------------------------------
__global__ void mean_kernel(const float* __restrict__ partials, float* __restrict__ out) {
    __shared__ float s[256];
    float a = 0.f;
    for (int i = threadIdx.x; i < NBLK_EDGE; i += 256) a += partials[i];
    s[threadIdx.x] = a;
    __syncthreads();
    for (int st = 128; st > 0; st >>= 1) {
        if ((int)threadIdx.x < st) s[threadIdx.x] += s[threadIdx.x + st];
        __syncthreads();
    }
    if (threadIdx.x == 0) out[2 * EHn] = s[0] / (float)EHn;
}

extern "C" void kernel_launch(void* const* d_in, const int* in_sizes, int n_in,
                              void* d_out, int out_size, void* d_ws, size_t ws_size,
                              hipStream_t stream) {
    const float* emb  = (const float*)d_in[0];
    const int*   src  = (const int*)d_in[1];
    const int*   dst  = (const int*)d_in[2];
    const float* vals = (const float*)d_in[3];
    const float* eps  = (const float*)d_in[4];
    const float* W1   = (const float*)d_in[5];
    const float* b1   = (const float*)d_in[6];
    const float* W2   = (const float*)d_in[7];
    const float* b2   = (const float*)d_in[8];
    float* out = (float*)d_out;

    char* ws = (char*)d_ws;
    __bf16* PQ      = (__bf16*)(ws + PQ_OFF);
    __bf16* bfrag   = (__bf16*)(ws + BFRAG_OFF);
    float*  partials = (float*)(ws + PART_OFF);

    hipLaunchKernelGGL(w1_repack_kernel, dim3(1), dim3(256), 0, stream, W1, bfrag);
    hipLaunchKernelGGL(node_proj_kernel, dim3((NN + 127) / 128), dim3(256), 0, stream,
                       emb, bfrag, PQ);
    hipLaunchKernelGGL(edge_kernel, dim3(NBLK_EDGE), dim3(256), 0, stream,
                       PQ, src, dst, vals, eps, b1, W2, b2, out, partials);
    hipLaunchKernelGGL(mean_kernel, dim3(1), dim3(256), 0, stream, partials, out);
}

// Round 2
// 65.165 us; speedup vs baseline: 2.4711x; 2.4711x over previous
//
#include <hip/hip_runtime.h>
#include <hip/hip_bf16.h>

#define NN 100000       // nodes
#define DD 128          // emb dim (PQ width: 64 P + 64 Q)
#define EHn 400000      // half-edge count
#define BIASc 1e-4f

using bf16x8 = __attribute__((ext_vector_type(8))) __bf16;
using f32x4  = __attribute__((ext_vector_type(4))) float;

// workspace layout
#define PQ_OFF    0
#define PQ_BYTES  ((size_t)NN * DD * 2)          // 25,600,000 (16B aligned)
#define BFRAG_OFF PQ_BYTES
#define BFRAG_BYTES (4 * 8 * 64 * 8 * 2)         // 32768
#define PART_OFF  (BFRAG_OFF + BFRAG_BYTES)
#define NBLK_EDGE 1563                            // ceil(400000/256)

// ---------------------------------------------------------------------------
// Kernel 1: repack W1 (fp32, [256][64] row-major) into bf16 MFMA B-fragments.
// W1cat[k][c] (k<128, c<128): c<64 -> W1[k][c], c>=64 -> W1[k+128][c-64].
// Fragment (t,f): k = t*32 + (lane>>4)*8 + j, col = f*16 + (lane&15), j=0..7.
// ---------------------------------------------------------------------------
__global__ void w1_repack_kernel(const float* __restrict__ W1, __bf16* __restrict__ bfrag) {
    #pragma unroll
    for (int i = 0; i < 64; ++i) {
        int idx = threadIdx.x + i * 256;          // 0..16383
        int j = idx & 7;
        int l = (idx >> 3) & 63;
        int f = (idx >> 9) & 7;
        int t = idx >> 12;
        int k = t * 32 + ((l >> 4) << 3) + j;
        int c = f * 16 + (l & 15);
        float v = (c < 64) ? W1[k * 64 + c] : W1[(k + 128) * 64 + (c - 64)];
        bfrag[idx] = (__bf16)v;
    }
}

// ---------------------------------------------------------------------------
// Kernel 2: PQ = emb @ W1cat (+ b1 folded into P columns). bf16 MFMA, fp32 acc.
// Block = 4 waves, 128 rows/block; wave handles 32 rows x 128 cols.
// ---------------------------------------------------------------------------
__global__ __launch_bounds__(256)
void node_proj_kernel(const float* __restrict__ emb, const __bf16* __restrict__ bfragG,
                      const float* __restrict__ b1, __bf16* __restrict__ PQ) {
    const int lane = threadIdx.x & 63;
    const int wave = threadIdx.x >> 6;
    const int rowBase = blockIdx.x * 128 + wave * 32;
    const int r16 = lane & 15;
    const int kg  = lane >> 4;

    f32x4 acc[2][8];
    #pragma unroll
    for (int m = 0; m < 2; ++m)
        #pragma unroll
        for (int f = 0; f < 8; ++f)
            acc[m][f] = (f32x4){0.f, 0.f, 0.f, 0.f};

    const bf16x8* bfrag = (const bf16x8*)bfragG;

    #pragma unroll
    for (int t = 0; t < 4; ++t) {
        bf16x8 af[2];
        #pragma unroll
        for (int m = 0; m < 2; ++m) {
            int row = rowBase + m * 16 + r16;
            row = row < NN ? row : NN - 1;        // clamp tail (stores guarded)
            const float* ap = emb + (size_t)row * DD + t * 32 + kg * 8;
            float4 lo = *(const float4*)ap;
            float4 hi = *(const float4*)(ap + 4);
            bf16x8 v;
            v[0] = (__bf16)lo.x; v[1] = (__bf16)lo.y; v[2] = (__bf16)lo.z; v[3] = (__bf16)lo.w;
            v[4] = (__bf16)hi.x; v[5] = (__bf16)hi.y; v[6] = (__bf16)hi.z; v[7] = (__bf16)hi.w;
            af[m] = v;
        }
        #pragma unroll
        for (int f = 0; f < 8; ++f) {
            bf16x8 bf = bfrag[(t * 8 + f) * 64 + lane];
            #pragma unroll
            for (int m = 0; m < 2; ++m)
                acc[m][f] = __builtin_amdgcn_mfma_f32_16x16x32_bf16(af[m], bf, acc[m][f], 0, 0, 0);
        }
    }

    // C/D layout: col = lane&15, row = (lane>>4)*4 + r. Fold b1 into P cols.
    #pragma unroll
    for (int m = 0; m < 2; ++m) {
        #pragma unroll
        for (int f = 0; f < 8; ++f) {
            #pragma unroll
            for (int r = 0; r < 4; ++r) {
                int row = rowBase + m * 16 + kg * 4 + r;
                int col = f * 16 + r16;
                float v = acc[m][f][r];
                if (col < 64) v += b1[col];
                if (row < NN) PQ[(size_t)row * DD + col] = (__bf16)v;
            }
        }
    }
}

// ---------------------------------------------------------------------------
// Kernel 3: per-edge gate. ONE LANE PER EDGE. Lane loads its P-row (128B) and
// Q-row (128B), lane-local fmaf dot with W2 (SGPR-uniform), concrete gate,
// two coalesced stores, block-reduce partial sum of gate weights.
// ---------------------------------------------------------------------------
__global__ __launch_bounds__(256)
void edge_kernel(const __bf16* __restrict__ PQ, const int* __restrict__ src,
                 const int* __restrict__ dst, const float* __restrict__ vals,
                 const float* __restrict__ eps_u, const float* __restrict__ W2,
                 const float* __restrict__ b2, float* __restrict__ out,
                 float* __restrict__ partials) {
    const int e = blockIdx.x * 256 + threadIdx.x;
    float wgate = 0.f;

    if (e < EHn) {
        const int s = src[e];
        const int d = dst[e];
        const uint4* prow = (const uint4*)(PQ + (size_t)s * DD);        // P half (+b1)
        const uint4* qrow = (const uint4*)(PQ + (size_t)d * DD + 64);   // Q half

        float acc0 = 0.f, acc1 = 0.f;
        #pragma unroll
        for (int c = 0; c < 8; ++c) {
            uint4 p = prow[c];
            uint4 q = qrow[c];
            const unsigned pw[4] = {p.x, p.y, p.z, p.w};
            const unsigned qw[4] = {q.x, q.y, q.z, q.w};
            #pragma unroll
            for (int k = 0; k < 4; ++k) {
                int i = c * 8 + k * 2;
                float pl = __uint_as_float(pw[k] << 16);
                float ph = __uint_as_float(pw[k] & 0xffff0000u);
                float ql = __uint_as_float(qw[k] << 16);
                float qh = __uint_as_float(qw[k] & 0xffff0000u);
                acc0 = fmaf(fmaxf(pl + ql, 0.f), W2[i], acc0);
                acc1 = fmaf(fmaxf(ph + qh, 0.f), W2[i + 1], acc1);
            }
        }
        float logit = acc0 + acc1 + b2[0];

        float u = eps_u[e];
        float epsv = fmaf(2.f * BIASc - 1.f, u, 1.f - BIASc);   // eps in [BIAS, 1-BIAS]
        float ome  = fmaf(1.f - 2.f * BIASc, u, BIASc);         // 1 - eps (no cancellation)
        float g = __logf(epsv) - __logf(ome) + logit;           // TEMP = 1
        wgate = 1.f / (1.f + __expf(-g));
        float nv = vals[e] * wgate;
        out[e] = nv;
        out[EHn + e] = nv;
    }

    // block reduction of gate weights -> partials[block]
    __shared__ float sred[256];
    sred[threadIdx.x] = wgate;
    __syncthreads();
    #pragma unroll
    for (int st = 128; st >= 64; st >>= 1) {
        if ((int)threadIdx.x < st) sred[threadIdx.x] += sred[threadIdx.x + st];
        __syncthreads();
    }
    if (threadIdx.x < 64) {
        float a = sred[threadIdx.x];
        #pragma unroll
        for (int off = 32; off > 0; off >>= 1)
            a += __shfl_xor(a, off, 64);
        if (threadIdx.x == 0) partials[blockIdx.x] = a;
    }
}

// ---------------------------------------------------------------------------
// Kernel 4: deterministic mean reduction over block partials.
// ---------------------------------------------------------------------------
__global__ void mean_kernel(const float* __restrict__ partials, float* __restrict__ out) {
    __shared__ float s[256];
    float a = 0.f;
    for (int i = threadIdx.x; i < NBLK_EDGE; i += 256) a += partials[i];
    s[threadIdx.x] = a;
    __syncthreads();
    for (int st = 128; st > 0; st >>= 1) {
        if ((int)threadIdx.x < st) s[threadIdx.x] += s[threadIdx.x + st];
        __syncthreads();
    }
    if (threadIdx.x == 0) out[2 * EHn] = s[0] / (float)EHn;
}

extern "C" void kernel_launch(void* const* d_in, const int* in_sizes, int n_in,
                              void* d_out, int out_size, void* d_ws, size_t ws_size,
                              hipStream_t stream) {
    const float* emb  = (const float*)d_in[0];
    const int*   src  = (const int*)d_in[1];
    const int*   dst  = (const int*)d_in[2];
    const float* vals = (const float*)d_in[3];
    const float* eps  = (const float*)d_in[4];
    const float* W1   = (const float*)d_in[5];
    const float* b1   = (const float*)d_in[6];
    const float* W2   = (const float*)d_in[7];
    const float* b2   = (const float*)d_in[8];
    float* out = (float*)d_out;

    char* ws = (char*)d_ws;
    __bf16* PQ       = (__bf16*)(ws + PQ_OFF);
    __bf16* bfrag    = (__bf16*)(ws + BFRAG_OFF);
    float*  partials = (float*)(ws + PART_OFF);

    hipLaunchKernelGGL(w1_repack_kernel, dim3(1), dim3(256), 0, stream, W1, bfrag);
    hipLaunchKernelGGL(node_proj_kernel, dim3((NN + 127) / 128), dim3(256), 0, stream,
                       emb, bfrag, b1, PQ);
    hipLaunchKernelGGL(edge_kernel, dim3(NBLK_EDGE), dim3(256), 0, stream,
                       PQ, src, dst, vals, eps, W2, b2, out, partials);
    hipLaunchKernelGGL(mean_kernel, dim3(1), dim3(256), 0, stream, partials, out);
}